// Round 1
// baseline (155.284 us; speedup 1.0000x reference)
//
#include <hip/hip_runtime.h>

// Problem constants (match reference): B=8192, P=32, D=128, V=100000
#define BB 8192
#define PP 32
#define DD 128

__global__ void hs_init_kernel(float* __restrict__ ws) {
    ws[0] = 0.0f;  // loss sum
    ws[1] = 0.0f;  // valid count
}

// One wave (64 lanes) per batch row b. Each 32-lane half handles one path
// position p: lane hl reads embed_row[hl*4 .. hl*4+3] (float4, 32*16B = 512B
// = one full D=128 row, perfectly coalesced), 5-step shfl_xor reduction gives
// the dot product within the half-wave.
__global__ __launch_bounds__(256) void hs_loss_kernel(
    const float* __restrict__ hidden,      // [B, D]
    const int*   __restrict__ path,        // [B, P]
    const int*   __restrict__ path_len,    // [B]
    const int*   __restrict__ code,        // [B, P]
    const float* __restrict__ embed,       // [V, D]
    float* __restrict__ ws)                // ws[0]=loss sum, ws[1]=count
{
    const int lane = threadIdx.x & 63;
    const int wave = threadIdx.x >> 6;       // 0..3
    const int b    = blockIdx.x * 4 + wave;  // grid = B/4 blocks
    const int half = lane >> 5;              // 0 or 1
    const int hl   = lane & 31;              // lane within half

    // hidden row, float4 per half-lane (both halves hold identical copies)
    const float4 h = ((const float4*)(hidden + (size_t)b * DD))[hl];
    const int len = path_len[b];

    float wsum = 0.0f;
    for (int p0 = 0; p0 < len; p0 += 2) {
        const int  p     = p0 + half;
        const bool valid = (p < len);
        // invalid half re-reads p0's row (harmless, keeps load uniform)
        const int idx = path[b * PP + (valid ? p : p0)];
        const float4 e = ((const float4*)(embed + (size_t)idx * DD))[hl];
        float dot = h.x * e.x + h.y * e.y + h.z * e.z + h.w * e.w;
        // reduce across the 32-lane half (xor masks < 32 stay within halves)
        dot += __shfl_xor(dot, 1);
        dot += __shfl_xor(dot, 2);
        dot += __shfl_xor(dot, 4);
        dot += __shfl_xor(dot, 8);
        dot += __shfl_xor(dot, 16);
        if (valid && hl == 0) {
            // loss = flag ? -log(sigmoid(dot)) : -log(1-sigmoid(dot))
            //      = softplus(flag ? -dot : dot), numerically stable form
            const float z = code[b * PP + p] ? -dot : dot;
            wsum += fmaxf(z, 0.0f) + log1pf(__expf(-fabsf(z)));
        }
    }

    // lanes 0 and 32 hold the two half-accumulators; combine into lane 0
    wsum += __shfl_xor(wsum, 32);

    __shared__ float s_loss[4];
    __shared__ float s_cnt[4];
    if (lane == 0) {
        s_loss[wave] = wsum;
        s_cnt[wave]  = (float)len;
    }
    __syncthreads();
    if (threadIdx.x == 0) {
        const float L = s_loss[0] + s_loss[1] + s_loss[2] + s_loss[3];
        const float C = s_cnt[0] + s_cnt[1] + s_cnt[2] + s_cnt[3];
        atomicAdd(&ws[0], L);   // device-scope by default on gfx950
        atomicAdd(&ws[1], C);
    }
}

__global__ void hs_finalize_kernel(const float* __restrict__ ws,
                                   float* __restrict__ out) {
    out[0] = ws[0] / ws[1];
}

extern "C" void kernel_launch(void* const* d_in, const int* in_sizes, int n_in,
                              void* d_out, int out_size, void* d_ws, size_t ws_size,
                              hipStream_t stream) {
    const float* hidden   = (const float*)d_in[0];  // [B, D] f32
    // d_in[1] = target (unused by the reference computation)
    const int*   path     = (const int*)d_in[2];    // [B, P]
    const int*   path_len = (const int*)d_in[3];    // [B]
    const int*   code     = (const int*)d_in[4];    // [B, P]
    const float* embed    = (const float*)d_in[5];  // [V, D] f32
    float* out = (float*)d_out;
    float* ws  = (float*)d_ws;

    hs_init_kernel<<<1, 1, 0, stream>>>(ws);
    hs_loss_kernel<<<BB / 4, 256, 0, stream>>>(hidden, path, path_len, code,
                                               embed, ws);
    hs_finalize_kernel<<<1, 1, 0, stream>>>(ws, out);
}

// Round 2
// 124.824 us; speedup vs baseline: 1.2440x; 1.2440x over previous
//
#include <hip/hip_runtime.h>

// Problem constants (match reference): B=8192, P=32, D=128, V=100000
#define BB 8192
#define PP 32
#define DD 128

// One block (1024 threads = 16 waves = 32 half-waves) per batch row b.
// Half-wave hw (0..31) handles path position p == hw: lane hl (0..31) reads
// embed_row[hl*4 .. hl*4+3] as float4 (32 lanes x 16B = 512B = one full
// D=128 row, perfectly coalesced), then a 5-step shfl_xor reduction within
// the half gives the dot product. All 32 gathers per block (and across the
// 8192 blocks) are independent -> maximal memory-level parallelism, no
// serial dependent-load loop (the round-1 bottleneck).
__global__ __launch_bounds__(1024) void hs_loss_kernel(
    const float* __restrict__ hidden,      // [B, D]
    const int*   __restrict__ path,        // [B, P]
    const int*   __restrict__ path_len,    // [B]
    const int*   __restrict__ code,        // [B, P]
    const float* __restrict__ embed,       // [V, D]
    float2* __restrict__ partials)         // [B] {loss_sum, valid_count}
{
    const int tid = threadIdx.x;
    const int b   = blockIdx.x;
    const int p   = tid >> 5;        // half-wave id == path position, 0..31
    const int hl  = tid & 31;        // lane within half

    const int len = path_len[b];     // uniform across block

    float lval = 0.0f;               // meaningful only at hl==0
    if (p < len) {
        const int idx = path[b * PP + p];
        const float4 h = ((const float4*)(hidden + (size_t)b  * DD))[hl];
        const float4 e = ((const float4*)(embed  + (size_t)idx * DD))[hl];
        float dot = h.x * e.x + h.y * e.y + h.z * e.z + h.w * e.w;
        // xor masks < 32 stay within the 32-lane half of the wave64
        dot += __shfl_xor(dot, 1);
        dot += __shfl_xor(dot, 2);
        dot += __shfl_xor(dot, 4);
        dot += __shfl_xor(dot, 8);
        dot += __shfl_xor(dot, 16);
        // loss = softplus(code ? -dot : dot)  (stable form of the BCE expr)
        const float z = code[b * PP + p] ? -dot : dot;
        lval = fmaxf(z, 0.0f) + log1pf(__expf(-fabsf(z)));
    }

    __shared__ float s_loss[PP];
    if (hl == 0) s_loss[p] = lval;   // invalid halves write 0
    __syncthreads();

    if (tid < PP) {
        float v = s_loss[tid];
        v += __shfl_xor(v, 1);
        v += __shfl_xor(v, 2);
        v += __shfl_xor(v, 4);
        v += __shfl_xor(v, 8);
        v += __shfl_xor(v, 16);
        if (tid == 0) partials[b] = make_float2(v, (float)len);
    }
}

// Single-block reduction of the 8192 per-block partials + final divide.
__global__ __launch_bounds__(1024) void hs_finalize_kernel(
    const float2* __restrict__ partials, float* __restrict__ out)
{
    const int tid = threadIdx.x;
    float ls = 0.0f, cs = 0.0f;
    #pragma unroll
    for (int k = 0; k < BB / 1024; ++k) {
        const float2 v = partials[tid + k * 1024];
        ls += v.x;
        cs += v.y;
    }
    // wave64 reduction
    #pragma unroll
    for (int m = 1; m <= 32; m <<= 1) {
        ls += __shfl_xor(ls, m);
        cs += __shfl_xor(cs, m);
    }
    __shared__ float s_l[16], s_c[16];
    const int wave = tid >> 6;
    if ((tid & 63) == 0) { s_l[wave] = ls; s_c[wave] = cs; }
    __syncthreads();
    if (tid == 0) {
        float L = 0.0f, C = 0.0f;
        #pragma unroll
        for (int w = 0; w < 16; ++w) { L += s_l[w]; C += s_c[w]; }
        out[0] = L / C;
    }
}

extern "C" void kernel_launch(void* const* d_in, const int* in_sizes, int n_in,
                              void* d_out, int out_size, void* d_ws, size_t ws_size,
                              hipStream_t stream) {
    const float* hidden   = (const float*)d_in[0];  // [B, D] f32
    // d_in[1] = target (unused by the reference computation)
    const int*   path     = (const int*)d_in[2];    // [B, P]
    const int*   path_len = (const int*)d_in[3];    // [B]
    const int*   code     = (const int*)d_in[4];    // [B, P]
    const float* embed    = (const float*)d_in[5];  // [V, D] f32
    float*  out      = (float*)d_out;
    float2* partials = (float2*)d_ws;               // 8192 * 8B = 64 KB

    hs_loss_kernel<<<BB, 1024, 0, stream>>>(hidden, path, path_len, code,
                                            embed, partials);
    hs_finalize_kernel<<<1, 1024, 0, stream>>>(partials, out);
}

// Round 3
// 114.875 us; speedup vs baseline: 1.3518x; 1.0866x over previous
//
#include <hip/hip_runtime.h>

// Problem constants (match reference): B=8192, P=32, D=128, V=100000
#define BB 8192
#define PP 32
#define DD 128

// One block (256 threads = 4 waves = 8 half-waves) per batch row b.
// Half-wave hw (0..7) handles the 4 path positions p = hw*4 .. hw*4+3:
//  - one int4 load grabs all 4 path indices (and one int4 the 4 codes),
//  - 4 independent float4 embed gathers issue back-to-back (lane hl reads
//    row[hl*4..hl*4+3]; 32 lanes x 16B = one full 512B row, coalesced),
//  - 4 dot products via 5-step shfl_xor reductions within the half.
// Per wave: 8 embed gathers in flight (round-2 had 2) -> 4x the
// memory-level parallelism that the latency-bound round-2 kernel lacked.
__global__ __launch_bounds__(256) void hs_loss_kernel(
    const float* __restrict__ hidden,      // [B, D]
    const int*   __restrict__ path,        // [B, P]
    const int*   __restrict__ path_len,    // [B]
    const int*   __restrict__ code,        // [B, P]
    const float* __restrict__ embed,       // [V, D]
    float2* __restrict__ partials)         // [B] {loss_sum, valid_count}
{
    const int tid = threadIdx.x;
    const int b   = blockIdx.x;
    const int hw  = tid >> 5;        // half-wave id, 0..7
    const int hl  = tid & 31;        // lane within half
    const int p0  = hw * 4;          // first path position of this half

    const int len = path_len[b];     // uniform across block

    float acc = 0.0f;                // meaningful only at hl==0
    if (p0 < len) {
        // 4 indices + 4 codes in one 16B load each (b*PP is 16B-aligned)
        const int4 idx4 = ((const int4*)(path + b * PP))[hw];
        const int4 cd4  = ((const int4*)(code + b * PP))[hw];
        const float4 h  = ((const float4*)(hidden + (size_t)b * DD))[hl];

        const int nv = min(len - p0, 4);
        const int idx[4] = {idx4.x, idx4.y, idx4.z, idx4.w};
        const int cd[4]  = {cd4.x, cd4.y, cd4.z, cd4.w};

        // issue all valid gathers before consuming any (max MLP)
        float4 e[4];
        #pragma unroll
        for (int j = 0; j < 4; ++j)
            if (j < nv) e[j] = ((const float4*)(embed + (size_t)idx[j] * DD))[hl];

        #pragma unroll
        for (int j = 0; j < 4; ++j) {
            if (j < nv) {
                float dot = h.x * e[j].x + h.y * e[j].y + h.z * e[j].z + h.w * e[j].w;
                // xor masks < 32 stay within the 32-lane half of the wave64
                dot += __shfl_xor(dot, 1);
                dot += __shfl_xor(dot, 2);
                dot += __shfl_xor(dot, 4);
                dot += __shfl_xor(dot, 8);
                dot += __shfl_xor(dot, 16);
                // loss = softplus(code ? -dot : dot) (stable BCE form)
                const float z = cd[j] ? -dot : dot;
                acc += fmaxf(z, 0.0f) + log1pf(__expf(-fabsf(z)));
            }
        }
    }

    __shared__ float s_loss[8];
    if (hl == 0) s_loss[hw] = acc;   // fully-invalid halves write 0
    __syncthreads();

    if (tid == 0) {
        float v = 0.0f;
        #pragma unroll
        for (int k = 0; k < 8; ++k) v += s_loss[k];
        partials[b] = make_float2(v, (float)len);
    }
}

// Single-block reduction of the 8192 per-block partials + final divide.
__global__ __launch_bounds__(1024) void hs_finalize_kernel(
    const float2* __restrict__ partials, float* __restrict__ out)
{
    const int tid = threadIdx.x;
    float ls = 0.0f, cs = 0.0f;
    #pragma unroll
    for (int k = 0; k < BB / 1024; ++k) {
        const float2 v = partials[tid + k * 1024];
        ls += v.x;
        cs += v.y;
    }
    // wave64 reduction
    #pragma unroll
    for (int m = 1; m <= 32; m <<= 1) {
        ls += __shfl_xor(ls, m);
        cs += __shfl_xor(cs, m);
    }
    __shared__ float s_l[16], s_c[16];
    const int wave = tid >> 6;
    if ((tid & 63) == 0) { s_l[wave] = ls; s_c[wave] = cs; }
    __syncthreads();
    if (tid == 0) {
        float L = 0.0f, C = 0.0f;
        #pragma unroll
        for (int w = 0; w < 16; ++w) { L += s_l[w]; C += s_c[w]; }
        out[0] = L / C;
    }
}

extern "C" void kernel_launch(void* const* d_in, const int* in_sizes, int n_in,
                              void* d_out, int out_size, void* d_ws, size_t ws_size,
                              hipStream_t stream) {
    const float* hidden   = (const float*)d_in[0];  // [B, D] f32
    // d_in[1] = target (unused by the reference computation)
    const int*   path     = (const int*)d_in[2];    // [B, P]
    const int*   path_len = (const int*)d_in[3];    // [B]
    const int*   code     = (const int*)d_in[4];    // [B, P]
    const float* embed    = (const float*)d_in[5];  // [V, D] f32
    float*  out      = (float*)d_out;
    float2* partials = (float2*)d_ws;               // 8192 * 8B = 64 KB

    hs_loss_kernel<<<BB, 256, 0, stream>>>(hidden, path, path_len, code,
                                           embed, partials);
    hs_finalize_kernel<<<1, 1024, 0, stream>>>(partials, out);
}

// Round 4
// 108.354 us; speedup vs baseline: 1.4331x; 1.0602x over previous
//
#include <hip/hip_runtime.h>

// Problem constants (match reference): B=8192, P=32, D=128, V=100000
#define BB 8192
#define PP 32
#define DD 128
#define RPB 8   // batch rows per block (256 threads / 32 positions)

// Lane-per-pair: thread t in a 256-thread block owns pair (b, p) with
// p = t&31, b_local = t>>5 (8 batch rows per block). The block first stages
// its 8 hidden rows (4 KB) into LDS with one coalesced float4 store per
// thread. Each valid lane then walks its embed row with 32 float4 loads
// (issued 8 at a time for memory-level parallelism; 3 of every 4 chunk
// loads are L1 line hits), dotting against broadcast LDS reads of the
// hidden row. No per-pair shuffles, ~1 addressing instr per load
// (immediate offsets), softplus on all lanes in parallel — this removes
// the ~55 VALU-cycles/pair overhead of the half-wave-per-pair scheme
// (round-2/3 showed VALUBusy 42% at only 10% HBM).
__global__ __launch_bounds__(256) void hs_loss_kernel(
    const float* __restrict__ hidden,      // [B, D]
    const int*   __restrict__ path,        // [B, P]
    const int*   __restrict__ path_len,    // [B]
    const int*   __restrict__ code,        // [B, P]
    const float* __restrict__ embed,       // [V, D]
    float2* __restrict__ partials)         // [grid] {loss_sum, valid_count}
{
    const int tid = threadIdx.x;
    const int p   = tid & 31;            // path position
    const int bl  = tid >> 5;            // local batch row, 0..7
    const int b   = blockIdx.x * RPB + bl;

    __shared__ float hlds[RPB * DD];     // 4 KB, no padding needed:
    // stage: thread t writes hidden[b][p*4 .. p*4+3]; per half-wave this is
    // 32 consecutive float4 = one 512B row, fully coalesced.
    ((float4*)hlds)[tid] = ((const float4*)hidden)[b * (DD / 4) + p];

    const int  len   = path_len[b];      // uniform per half-wave
    const bool valid = (p < len);

    __syncthreads();

    float loss = 0.0f;
    if (valid) {
        const int idx = path[b * PP + p];   // coalesced per half-wave
        const int cd  = code[b * PP + p];
        const float4* __restrict__ erow = (const float4*)(embed + (size_t)idx * DD);
        const float4* __restrict__ hrow = (const float4*)(hlds + bl * DD);

        float acc = 0.0f;
        #pragma unroll
        for (int c0 = 0; c0 < DD / 4; c0 += 8) {
            // batch 8 independent global loads before consuming any
            float4 e[8];
            #pragma unroll
            for (int j = 0; j < 8; ++j) e[j] = erow[c0 + j];
            #pragma unroll
            for (int j = 0; j < 8; ++j) {
                const float4 h = hrow[c0 + j];  // same-addr LDS broadcast
                acc += e[j].x * h.x + e[j].y * h.y
                     + e[j].z * h.z + e[j].w * h.w;
            }
        }
        // loss = softplus(code ? -dot : dot), stable BCE form; fast-math
        // __logf/__expf are fine: z is small (dot std ~0.23), final output
        // is a mean of 131K terms vs a 1.4e-2 absmax threshold.
        const float z = cd ? -acc : acc;
        loss = fmaxf(z, 0.0f) + __logf(1.0f + __expf(-fabsf(z)));
    }

    // valid count via ballot (counts exactly sum(len) over the block)
    const unsigned long long bal = __ballot(valid);

    // wave64 reduction of loss
    #pragma unroll
    for (int m = 1; m <= 32; m <<= 1) loss += __shfl_xor(loss, m);

    __shared__ float s_l[4], s_c[4];
    const int wv = tid >> 6;
    if ((tid & 63) == 0) {
        s_l[wv] = loss;
        s_c[wv] = (float)__popcll(bal);
    }
    __syncthreads();
    if (tid == 0) {
        partials[blockIdx.x] = make_float2(s_l[0] + s_l[1] + s_l[2] + s_l[3],
                                           s_c[0] + s_c[1] + s_c[2] + s_c[3]);
    }
}

// Single-block reduction of the 1024 per-block partials + final divide.
__global__ __launch_bounds__(1024) void hs_finalize_kernel(
    const float2* __restrict__ partials, float* __restrict__ out)
{
    const int tid = threadIdx.x;
    const float2 v = partials[tid];      // grid of loss kernel == 1024
    float ls = v.x, cs = v.y;
    #pragma unroll
    for (int m = 1; m <= 32; m <<= 1) {
        ls += __shfl_xor(ls, m);
        cs += __shfl_xor(cs, m);
    }
    __shared__ float s_l[16], s_c[16];
    const int wave = tid >> 6;
    if ((tid & 63) == 0) { s_l[wave] = ls; s_c[wave] = cs; }
    __syncthreads();
    if (tid == 0) {
        float L = 0.0f, C = 0.0f;
        #pragma unroll
        for (int w = 0; w < 16; ++w) { L += s_l[w]; C += s_c[w]; }
        out[0] = L / C;
    }
}

extern "C" void kernel_launch(void* const* d_in, const int* in_sizes, int n_in,
                              void* d_out, int out_size, void* d_ws, size_t ws_size,
                              hipStream_t stream) {
    const float* hidden   = (const float*)d_in[0];  // [B, D] f32
    // d_in[1] = target (unused by the reference computation)
    const int*   path     = (const int*)d_in[2];    // [B, P]
    const int*   path_len = (const int*)d_in[3];    // [B]
    const int*   code     = (const int*)d_in[4];    // [B, P]
    const float* embed    = (const float*)d_in[5];  // [V, D] f32
    float*  out      = (float*)d_out;
    float2* partials = (float2*)d_ws;               // 1024 * 8B = 8 KB

    hs_loss_kernel<<<BB / RPB, 256, 0, stream>>>(hidden, path, path_len, code,
                                                 embed, partials);
    hs_finalize_kernel<<<1, 1024, 0, stream>>>(partials, out);
}